// Round 7
// baseline (429.897 us; speedup 1.0000x reference)
//
#include <hip/hip_runtime.h>
#include <hip/hip_bf16.h>

#define D 128
#define BSHIFT 7            // bucket = src >> 7  (128 users / bucket)
#define BUCK 128
#define CHUNK 4096          // edges per sort block
#define NBMAX 1024

typedef short bf16x8 __attribute__((ext_vector_type(8)));
typedef float f32x4 __attribute__((ext_vector_type(4)));
typedef float f32x2 __attribute__((ext_vector_type(2)));

__device__ __forceinline__ unsigned short f2bf(float x) {
    __hip_bfloat16 h = __float2bfloat16(x);
    return *reinterpret_cast<unsigned short*>(&h);
}
__device__ __forceinline__ float bflo(unsigned int w) { return __uint_as_float(w << 16); }
__device__ __forceinline__ float bfhi(unsigned int w) { return __uint_as_float(w & 0xffff0000u); }

// tanh-form GELU pair: gelu(z) = z - z/(1+q), q = exp2(z*(2.3022646 + 0.1029466 z^2))
__device__ __forceinline__ f32x2 gelu2(f32x2 z) {
    f32x2 z2 = z * z;
    f32x2 c1 = {0.1029466f, 0.1029466f};
    f32x2 c0 = {2.3022646f, 2.3022646f};
    f32x2 xe = z * __builtin_elementwise_fma(z2, c1, c0);
    f32x2 q;
    q.x = __builtin_amdgcn_exp2f(xe.x);
    q.y = __builtin_amdgcn_exp2f(xe.y);
    f32x2 d = q + 1.0f;
    f32x2 r;
    r.x = __builtin_amdgcn_rcpf(d.x);
    r.y = __builtin_amdgcn_rcpf(d.y);
    return __builtin_elementwise_fma(-z, r, z);
}

__device__ __forceinline__ float gelu_erf(float z) {
    float y = fabsf(z) * 0.70710678118654752f;
    float t = __builtin_amdgcn_rcpf(1.0f + 0.3275911f * y);
    float poly = ((((1.061405429f * t - 1.453152027f) * t + 1.421413741f) * t
                   - 0.284496736f) * t + 0.254829592f) * t;
    float e = __expf(-y * y);
    float erfv = 1.0f - poly * e;
    erfv = copysignf(erfv, z);
    return 0.5f * z * (1.0f + erfv);
}

// ---------------- K1: W1T fragment transpose | Wc | per-chunk histograms ----------------
__global__ __launch_bounds__(256) void prep_count(const float* __restrict__ W1,
                                                  const float* __restrict__ W2,
                                                  const float* __restrict__ Wp,
                                                  const int* __restrict__ src,
                                                  int E, int NB, int NBLK,
                                                  unsigned short* __restrict__ W1T,
                                                  unsigned short* __restrict__ Wcbf,
                                                  int* __restrict__ cnt) {
    __shared__ int lh[NBMAX];
    const int b = blockIdx.x, t = threadIdx.x;
    if (b < 64) {
        int o0 = b * 1024 + t * 4;
        unsigned short v[4];
        #pragma unroll
        for (int jj = 0; jj < 4; ++jj) {
            int o = o0 + jj;
            int j = o & 7, l = (o >> 3) & 63, kk = (o >> 9) & 3, n = (o >> 11) & 7, h = o >> 14;
            int row = h * 128 + kk * 32 + (l >> 4) * 8 + j;
            int col = n * 16 + (l & 15);
            v[jj] = f2bf(W1[(size_t)row * D + col]);
        }
        *reinterpret_cast<ushort4*>(&W1T[o0]) = make_ushort4(v[0], v[1], v[2], v[3]);
    } else if (b == 64) {
        #pragma unroll
        for (int i = 0; i < 8; ++i) {
            int idx = i * 256 + t;
            int col = idx >> 7, k = idx & 127;
            float acc = 0.f;
            if (col < 5) {
                #pragma unroll 8
                for (int j = 0; j < D; ++j) acc += W2[k * D + j] * Wp[j * 5 + col];
            }
            Wcbf[col * D + k] = f2bf(acc);
        }
    } else {
        const int blk = b - 65;
        for (int i = t; i < NB; i += 256) lh[i] = 0;
        __syncthreads();
        const int e0 = blk * CHUNK;
        const int e1 = min(e0 + CHUNK, E);
        for (int e = e0 + t; e < e1; e += 256) atomicAdd(&lh[src[e] >> BSHIFT], 1);
        __syncthreads();
        for (int k = t; k < NB; k += 256) cnt[k * NBLK + blk] = lh[k];
    }
}

// ---------------- K2: node transform (blocks < nbU+nbM) | base scan (last block) ----------------
__global__ __launch_bounds__(512) void node_scan(const float* __restrict__ uf,
                                                 const float* __restrict__ vf,
                                                 const unsigned short* __restrict__ W1T,
                                                 int NU, int NM, int nbU, int nbM,
                                                 unsigned short* __restrict__ Abf,
                                                 unsigned short* __restrict__ Bbf,
                                                 const int* __restrict__ cnt,
                                                 int NB, int NBLK,
                                                 int* __restrict__ base) {
    __shared__ unsigned short sW[16384];
    __shared__ int ps[512];
    const int b = blockIdx.x, t = threadIdx.x;

    if (b < nbU + nbM) {
        const float* feat;
        unsigned short* outp;
        int Nn, tile, h;
        if (b < nbU) { feat = uf; outp = Abf; Nn = NU; tile = b;       h = 0; }
        else         { feat = vf; outp = Bbf; Nn = NM; tile = b - nbU; h = 1; }
        const int r0 = tile * 256;
        {
            const uint4* srcp = reinterpret_cast<const uint4*>(W1T + (size_t)h * 16384);
            uint4* dstp = reinterpret_cast<uint4*>(sW);
            #pragma unroll
            for (int i = 0; i < 4; ++i) dstp[i * 512 + t] = srcp[i * 512 + t];
        }
        __syncthreads();

        const int wv = t >> 6, l = t & 63;
        const int m16 = l & 15, g4 = l >> 4;

        #pragma unroll
        for (int t16 = 0; t16 < 2; ++t16) {
            const int rowbase = r0 + wv * 32 + t16 * 16;
            if (rowbase >= Nn) break;
            const int arow = rowbase + m16;
            const bool rok = arow < Nn;
            const float* rp = feat + (size_t)(rok ? arow : 0) * D;

            union { bf16x8 v; unsigned short u[8]; } afr[4];
            #pragma unroll
            for (int kk = 0; kk < 4; ++kk) {
                int k0 = kk * 32 + g4 * 8;
                float4 f0 = make_float4(0.f, 0.f, 0.f, 0.f), f1 = f0;
                if (rok) {
                    f0 = *reinterpret_cast<const float4*>(rp + k0);
                    f1 = *reinterpret_cast<const float4*>(rp + k0 + 4);
                }
                afr[kk].u[0] = f2bf(f0.x); afr[kk].u[1] = f2bf(f0.y);
                afr[kk].u[2] = f2bf(f0.z); afr[kk].u[3] = f2bf(f0.w);
                afr[kk].u[4] = f2bf(f1.x); afr[kk].u[5] = f2bf(f1.y);
                afr[kk].u[6] = f2bf(f1.z); afr[kk].u[7] = f2bf(f1.w);
            }
            #pragma unroll
            for (int n = 0; n < 8; ++n) {
                f32x4 acc = (f32x4){0.f, 0.f, 0.f, 0.f};
                #pragma unroll
                for (int kk = 0; kk < 4; ++kk) {
                    bf16x8 bfr = *reinterpret_cast<const bf16x8*>(&sW[((n * 4 + kk) * 64 + l) * 8]);
                    acc = __builtin_amdgcn_mfma_f32_16x16x32_bf16(afr[kk].v, bfr, acc, 0, 0, 0);
                }
                #pragma unroll
                for (int r = 0; r < 4; ++r) {
                    int row = rowbase + g4 * 4 + r;
                    if (row < Nn) outp[(size_t)row * D + n * 16 + m16] = f2bf(acc[r]);
                }
            }
        }
    } else {
        // scan block: thread t owns buckets 2t, 2t+1
        const int k0 = 2 * t, k1 = 2 * t + 1;
        int t0 = 0, t1 = 0;
        if (k0 < NB) for (int bb = 0; bb < NBLK; ++bb) t0 += cnt[k0 * NBLK + bb];
        if (k1 < NB) for (int bb = 0; bb < NBLK; ++bb) t1 += cnt[k1 * NBLK + bb];
        ps[t] = t0 + t1;
        __syncthreads();
        for (int off = 1; off < 512; off <<= 1) {
            int v = (t >= off) ? ps[t - off] : 0;
            __syncthreads();
            ps[t] += v;
            __syncthreads();
        }
        int start = ps[t] - (t0 + t1);
        if (k0 < NB) {
            int run = start;
            for (int bb = 0; bb < NBLK; ++bb) { base[k0 * NBLK + bb] = run; run += cnt[k0 * NBLK + bb]; }
        }
        if (k1 < NB) {
            int run = start + t0;
            for (int bb = 0; bb < NBLK; ++bb) { base[k1 * NBLK + bb] = run; run += cnt[k1 * NBLK + bb]; }
        }
    }
}

// ---------------- K3: scatter with per-block LDS cursors (no global atomics) ----------------
__global__ __launch_bounds__(256) void sort_scatter(const int* __restrict__ src,
                                                    const int* __restrict__ dst,
                                                    int E, int NB, int NBLK,
                                                    const int* __restrict__ base,
                                                    uint2* __restrict__ sd,
                                                    int* __restrict__ eid) {
    __shared__ int cur[NBMAX];
    const int blk = blockIdx.x, t = threadIdx.x;
    for (int k = t; k < NB; k += 256) cur[k] = base[k * NBLK + blk];
    __syncthreads();
    const int e0 = blk * CHUNK;
    const int e1 = min(e0 + CHUNK, E);
    for (int e = e0 + t; e < e1; e += 256) {
        int s = src[e];
        int d = dst[e];
        int pos = atomicAdd(&cur[s >> BSHIFT], 1);
        sd[pos] = make_uint2((unsigned)s, (unsigned)d);
        eid[pos] = e;
    }
}

// ---------------- K4: edge kernel, one block per bucket, A staged in swizzled LDS ----------------
__global__ __launch_bounds__(512) void edge_bucket(const unsigned short* __restrict__ A,
                                                   const unsigned short* __restrict__ B,
                                                   const uint2* __restrict__ sd,
                                                   const int* __restrict__ eid,
                                                   const unsigned short* __restrict__ Wcbf,
                                                   const int* __restrict__ base,
                                                   float* __restrict__ out,
                                                   int E, int NU, int NB, int NBLK) {
    __shared__ uint4 sA[BUCK * 16];   // 32KB, 16B-slot XOR swizzle
    const int k = blockIdx.x, t = threadIdx.x;
    const int rowbase = k << BSHIFT;

    // stage A rows of this bucket (coalesced global read, swizzled LDS write)
    #pragma unroll
    for (int i = t; i < BUCK * 16; i += 512) {
        int r = i >> 4, s = i & 15;
        uint4 v = (uint4){0u, 0u, 0u, 0u};
        if (rowbase + r < NU)
            v = *reinterpret_cast<const uint4*>(&A[(((size_t)(rowbase + r)) << 7) + s * 8]);
        sA[(r << 4) | (s ^ (r & 7))] = v;
    }

    const int l = t & 63, er = l & 15, quad = l >> 4, wv = t >> 6;
    bf16x8 wfrag[4];
    #pragma unroll
    for (int kk = 0; kk < 4; ++kk)
        wfrag[kk] = *reinterpret_cast<const bf16x8*>(&Wcbf[er * D + kk * 32 + quad * 8]);

    const int e0 = base[k * NBLK];
    const int e1 = (k + 1 < NB) ? base[(k + 1) * NBLK] : E;
    __syncthreads();

    const int len = e1 - e0;
    const int G = (len + 15) >> 4;
    for (int g = wv; g < G; g += 8) {
        const int ebase = e0 + g * 16;
        const int ee = min(ebase + er, e1 - 1);
        uint2 sdv = sd[ee];
        const int rr = (int)sdv.x - rowbase;   // 0..BUCK-1

        uint4 av[4];
        #pragma unroll
        for (int kk = 0; kk < 4; ++kk)
            av[kk] = sA[(rr << 4) | (((kk << 2) | quad) ^ (rr & 7))];

        const unsigned short* bp = B + ((size_t)sdv.y << 7) + quad * 8;
        uint4 bv[4];
        #pragma unroll
        for (int kk = 0; kk < 4; ++kk)
            bv[kk] = *reinterpret_cast<const uint4*>(bp + kk * 32);

        const int eb = ebase + quad * 4;
        int evr[4];
        #pragma unroll
        for (int r = 0; r < 4; ++r) evr[r] = eid[min(eb + r, E - 1)];

        f32x4 acc = (f32x4){0.f, 0.f, 0.f, 0.f};
        #pragma unroll
        for (int kk = 0; kk < 4; ++kk) {
            unsigned int aw[4] = {av[kk].x, av[kk].y, av[kk].z, av[kk].w};
            unsigned int bw[4] = {bv[kk].x, bv[kk].y, bv[kk].z, bv[kk].w};
            union { bf16x8 v; unsigned short u[8]; } frag;
            #pragma unroll
            for (int pp = 0; pp < 4; ++pp) {
                f32x2 za = {bflo(aw[pp]), bfhi(aw[pp])};
                f32x2 zb = {bflo(bw[pp]), bfhi(bw[pp])};
                f32x2 gl = gelu2(za + zb);
                frag.u[2 * pp]     = f2bf(gl.x);
                frag.u[2 * pp + 1] = f2bf(gl.y);
            }
            acc = __builtin_amdgcn_mfma_f32_16x16x32_bf16(frag.v, wfrag[kk], acc, 0, 0, 0);
        }

        #pragma unroll
        for (int r = 0; r < 4; ++r) {
            int e = eb + r;
            if (er < 5 && e < e1) out[(size_t)evr[r] * 5 + er] = acc[r];
        }
    }
}

// ---------------- mid-tier edge (unsorted, R2-proven) ----------------
__global__ __launch_bounds__(256, 4) void edge_unsorted(const unsigned short* __restrict__ A,
                                                        const unsigned short* __restrict__ B,
                                                        const int* __restrict__ src,
                                                        const int* __restrict__ dst,
                                                        const unsigned short* __restrict__ Wcbf,
                                                        float* __restrict__ out, int E) {
    const int l    = threadIdx.x & 63;
    const int er   = l & 15;
    const int quad = l >> 4;
    const int wid  = blockIdx.x * 4 + (threadIdx.x >> 6);
    const int nw   = gridDim.x * 4;

    bf16x8 wfrag[4];
    #pragma unroll
    for (int kk = 0; kk < 4; ++kk)
        wfrag[kk] = *reinterpret_cast<const bf16x8*>(&Wcbf[er * D + kk * 32 + quad * 8]);

    const int P = (E + 31) >> 5;
    if (wid >= P) return;
    const int Emax = E - 1;

    int ia = wid * 32 + er, ib = ia + 16;
    int sa = src[min(ia, Emax)], da = dst[min(ia, Emax)];
    int sb = src[min(ib, Emax)], db = dst[min(ib, Emax)];

    for (int p = wid; p < P; p += nw) {
        int pn = p + nw;
        int pc = pn < P ? pn : p;
        int ja = pc * 32 + er, jb = ja + 16;
        int san = src[min(ja, Emax)], dan = dst[min(ja, Emax)];
        int sbn = src[min(jb, Emax)], dbn = dst[min(jb, Emax)];

        const unsigned short* apA = A + ((size_t)sa << 7) + quad * 8;
        const unsigned short* bpA = B + ((size_t)da << 7) + quad * 8;
        const unsigned short* apB = A + ((size_t)sb << 7) + quad * 8;
        const unsigned short* bpB = B + ((size_t)db << 7) + quad * 8;
        uint4 a0[4], b0[4], a1[4], b1[4];
        #pragma unroll
        for (int kk = 0; kk < 4; ++kk) {
            a0[kk] = *reinterpret_cast<const uint4*>(apA + kk * 32);
            b0[kk] = *reinterpret_cast<const uint4*>(bpA + kk * 32);
            a1[kk] = *reinterpret_cast<const uint4*>(apB + kk * 32);
            b1[kk] = *reinterpret_cast<const uint4*>(bpB + kk * 32);
        }

        f32x4 accA = (f32x4){0.f, 0.f, 0.f, 0.f};
        f32x4 accB = accA;
        #pragma unroll
        for (int kk = 0; kk < 4; ++kk) {
            unsigned int aw[4] = {a0[kk].x, a0[kk].y, a0[kk].z, a0[kk].w};
            unsigned int bw[4] = {b0[kk].x, b0[kk].y, b0[kk].z, b0[kk].w};
            union { bf16x8 v; unsigned short u[8]; } frag;
            #pragma unroll
            for (int pp = 0; pp < 4; ++pp) {
                f32x2 za = {bflo(aw[pp]), bfhi(aw[pp])};
                f32x2 zb = {bflo(bw[pp]), bfhi(bw[pp])};
                f32x2 g = gelu2(za + zb);
                frag.u[2 * pp]     = f2bf(g.x);
                frag.u[2 * pp + 1] = f2bf(g.y);
            }
            accA = __builtin_amdgcn_mfma_f32_16x16x32_bf16(frag.v, wfrag[kk], accA, 0, 0, 0);
        }
        #pragma unroll
        for (int kk = 0; kk < 4; ++kk) {
            unsigned int aw[4] = {a1[kk].x, a1[kk].y, a1[kk].z, a1[kk].w};
            unsigned int bw[4] = {b1[kk].x, b1[kk].y, b1[kk].z, b1[kk].w};
            union { bf16x8 v; unsigned short u[8]; } frag;
            #pragma unroll
            for (int pp = 0; pp < 4; ++pp) {
                f32x2 za = {bflo(aw[pp]), bfhi(aw[pp])};
                f32x2 zb = {bflo(bw[pp]), bfhi(bw[pp])};
                f32x2 g = gelu2(za + zb);
                frag.u[2 * pp]     = f2bf(g.x);
                frag.u[2 * pp + 1] = f2bf(g.y);
            }
            accB = __builtin_amdgcn_mfma_f32_16x16x32_bf16(frag.v, wfrag[kk], accB, 0, 0, 0);
        }

        int e0 = p << 5;
        #pragma unroll
        for (int r = 0; r < 4; ++r) {
            int eA = e0 + quad * 4 + r;
            if (er < 5 && eA < E) out[(size_t)eA * 5 + er] = accA[r];
        }
        #pragma unroll
        for (int r = 0; r < 4; ++r) {
            int eB = e0 + 16 + quad * 4 + r;
            if (er < 5 && eB < E) out[(size_t)eB * 5 + er] = accB[r];
        }
        sa = san; da = dan; sb = sbn; db = dbn;
    }
}

// ---------------- fallback (ws too small): fully fused per-edge ----------------
__global__ __launch_bounds__(256) void fused_fallback(const float* __restrict__ uf,
                                                      const float* __restrict__ vf,
                                                      const int* __restrict__ src,
                                                      const int* __restrict__ dst,
                                                      const float* __restrict__ W1,
                                                      const float* __restrict__ W2,
                                                      const float* __restrict__ Wp,
                                                      float* __restrict__ out, int E) {
    __shared__ unsigned short sW[256 * 128];
    __shared__ float sWc[5 * 128];
    __shared__ float sH[4][256];
    const int t = threadIdx.x;
    #pragma unroll
    for (int i = 0; i < 32; ++i) {
        int f = (i * 256 + t) * 4;
        float4 v = *reinterpret_cast<const float4*>(&W1[f]);
        sW[f + 0] = f2bf(v.x); sW[f + 1] = f2bf(v.y);
        sW[f + 2] = f2bf(v.z); sW[f + 3] = f2bf(v.w);
    }
    for (int idx = t; idx < 640; idx += 256) {
        int c = idx >> 7, k = idx & 127;
        float a = 0.f;
        for (int m = 0; m < 128; ++m) a += W2[k * 128 + m] * Wp[m * 5 + c];
        sWc[c * 128 + k] = a;
    }
    __syncthreads();
    const int wid = t >> 6, l = t & 63;
    const int nw = gridDim.x * 4;
    for (int e = blockIdx.x * 4 + wid; e < E; e += nw) {
        int s = src[e], d0 = dst[e];
        float2 hu = *reinterpret_cast<const float2*>(&uf[(size_t)s * 128 + 2 * l]);
        float2 hv = *reinterpret_cast<const float2*>(&vf[(size_t)d0 * 128 + 2 * l]);
        sH[wid][2 * l] = hu.x; sH[wid][2 * l + 1] = hu.y;
        sH[wid][128 + 2 * l] = hv.x; sH[wid][128 + 2 * l + 1] = hv.y;
        __builtin_amdgcn_wave_barrier();
        float z0 = 0.f, z1 = 0.f;
        for (int k = 0; k < 256; ++k) {
            float h = sH[wid][k];
            z0 += h * __uint_as_float((unsigned int)sW[k * 128 + l] << 16);
            z1 += h * __uint_as_float((unsigned int)sW[k * 128 + l + 64] << 16);
        }
        float g0 = gelu_erf(z0), g1 = gelu_erf(z1);
        float acc[5];
        #pragma unroll
        for (int c = 0; c < 5; ++c)
            acc[c] = g0 * sWc[c * 128 + l] + g1 * sWc[c * 128 + l + 64];
        #pragma unroll
        for (int c = 0; c < 5; ++c) {
            float v = acc[c];
            v += __shfl_xor(v, 1);  v += __shfl_xor(v, 2);
            v += __shfl_xor(v, 4);  v += __shfl_xor(v, 8);
            v += __shfl_xor(v, 16); v += __shfl_xor(v, 32);
            acc[c] = v;
        }
        float v = acc[0];
        if (l == 1) v = acc[1];
        if (l == 2) v = acc[2];
        if (l == 3) v = acc[3];
        if (l == 4) v = acc[4];
        if (l < 5) out[(size_t)e * 5 + l] = v;
        __builtin_amdgcn_wave_barrier();
    }
}

extern "C" void kernel_launch(void* const* d_in, const int* in_sizes, int n_in,
                              void* d_out, int out_size, void* d_ws, size_t ws_size,
                              hipStream_t stream) {
    const float* ufeat = (const float*)d_in[0];
    const float* ifeat = (const float*)d_in[1];
    const int*   src   = (const int*)d_in[2];
    const int*   dst   = (const int*)d_in[3];
    const float* W1    = (const float*)d_in[4];
    const float* W2    = (const float*)d_in[5];
    const float* Wp    = (const float*)d_in[6];
    float* out = (float*)d_out;

    const int NU = in_sizes[0] / D;
    const int NM = in_sizes[1] / D;
    const int E  = in_sizes[2];
    const int NB   = (NU + BUCK - 1) >> BSHIFT;
    const int NBLK = (E + CHUNK - 1) / CHUNK;

    size_t cur = 0;
    auto alloc = [&](size_t bytes) { size_t o = cur; cur = (cur + bytes + 255) & ~(size_t)255; return o; };
    size_t off_Wc   = alloc(4096);
    size_t off_W1T  = alloc(65536);
    size_t off_A    = alloc((size_t)NU * D * 2);
    size_t off_B    = alloc((size_t)NM * D * 2);
    size_t need_mid = cur;
    size_t off_cnt  = alloc((size_t)NB * NBLK * 4);
    size_t off_base = alloc((size_t)NB * NBLK * 4);
    size_t off_sd   = alloc((size_t)E * 8);
    size_t off_eid  = alloc((size_t)E * 4);
    size_t need_full = cur;

    if (ws_size >= need_mid) {
        unsigned short* Wcbf = (unsigned short*)((char*)d_ws + off_Wc);
        unsigned short* W1T  = (unsigned short*)((char*)d_ws + off_W1T);
        unsigned short* Abf  = (unsigned short*)((char*)d_ws + off_A);
        unsigned short* Bbf  = (unsigned short*)((char*)d_ws + off_B);
        int nbU = (NU + 255) / 256, nbM = (NM + 255) / 256;

        if (ws_size >= need_full && NB <= NBMAX && NB >= 2) {
            int*   cnt  = (int*)((char*)d_ws + off_cnt);
            int*   base = (int*)((char*)d_ws + off_base);
            uint2* sd   = (uint2*)((char*)d_ws + off_sd);
            int*   eid  = (int*)((char*)d_ws + off_eid);

            prep_count<<<dim3(65 + NBLK), dim3(256), 0, stream>>>(W1, W2, Wp, src, E, NB, NBLK,
                                                                  W1T, Wcbf, cnt);
            node_scan<<<dim3(nbU + nbM + 1), dim3(512), 0, stream>>>(ufeat, ifeat, W1T, NU, NM,
                                                                     nbU, nbM, Abf, Bbf,
                                                                     cnt, NB, NBLK, base);
            sort_scatter<<<dim3(NBLK), dim3(256), 0, stream>>>(src, dst, E, NB, NBLK, base, sd, eid);
            edge_bucket<<<dim3(NB), dim3(512), 0, stream>>>(Abf, Bbf, sd, eid, Wcbf, base,
                                                            out, E, NU, NB, NBLK);
        } else {
            prep_count<<<dim3(65), dim3(256), 0, stream>>>(W1, W2, Wp, src, E, NB, NBLK,
                                                           W1T, Wcbf, (int*)((char*)d_ws + off_Wc));
            node_scan<<<dim3(nbU + nbM), dim3(512), 0, stream>>>(ufeat, ifeat, W1T, NU, NM,
                                                                 nbU, nbM, Abf, Bbf,
                                                                 (const int*)W1T, 0, 0, (int*)0);
            edge_unsorted<<<dim3(2048), dim3(256), 0, stream>>>(Abf, Bbf, src, dst, Wcbf, out, E);
        }
    } else {
        fused_fallback<<<dim3(4096), dim3(256), 0, stream>>>(ufeat, ifeat, src, dst,
                                                             W1, W2, Wp, out, E);
    }
}

// Round 8
// 163.265 us; speedup vs baseline: 2.6331x; 2.6331x over previous
//
#include <hip/hip_runtime.h>
#include <hip/hip_bf16.h>

#define D 128
#define BSHIFT 7            // bucket = src >> 7  (128 users / bucket)
#define BUCK 128
#define CHUNK 16384         // edges per sort chunk
#define NBMAX 1024

typedef short bf16x8 __attribute__((ext_vector_type(8)));
typedef float f32x4 __attribute__((ext_vector_type(4)));
typedef float f32x2 __attribute__((ext_vector_type(2)));

__device__ __forceinline__ unsigned short f2bf(float x) {
    __hip_bfloat16 h = __float2bfloat16(x);
    return *reinterpret_cast<unsigned short*>(&h);
}
__device__ __forceinline__ float bflo(unsigned int w) { return __uint_as_float(w << 16); }
__device__ __forceinline__ float bfhi(unsigned int w) { return __uint_as_float(w & 0xffff0000u); }

// tanh-form GELU pair: gelu(z) = z - z/(1+q), q = exp2(z*(2.3022646 + 0.1029466 z^2))
__device__ __forceinline__ f32x2 gelu2(f32x2 z) {
    f32x2 z2 = z * z;
    f32x2 c1 = {0.1029466f, 0.1029466f};
    f32x2 c0 = {2.3022646f, 2.3022646f};
    f32x2 xe = z * __builtin_elementwise_fma(z2, c1, c0);
    f32x2 q;
    q.x = __builtin_amdgcn_exp2f(xe.x);
    q.y = __builtin_amdgcn_exp2f(xe.y);
    f32x2 d = q + 1.0f;
    f32x2 r;
    r.x = __builtin_amdgcn_rcpf(d.x);
    r.y = __builtin_amdgcn_rcpf(d.y);
    return __builtin_elementwise_fma(-z, r, z);
}

__device__ __forceinline__ float gelu_erf(float z) {
    float y = fabsf(z) * 0.70710678118654752f;
    float t = __builtin_amdgcn_rcpf(1.0f + 0.3275911f * y);
    float poly = ((((1.061405429f * t - 1.453152027f) * t + 1.421413741f) * t
                   - 0.284496736f) * t + 0.254829592f) * t;
    float e = __expf(-y * y);
    float erfv = 1.0f - poly * e;
    erfv = copysignf(erfv, z);
    return 0.5f * z * (1.0f + erfv);
}

// ---------------- K1: W1T fragment transpose | Wc | per-chunk histograms ----------------
__global__ __launch_bounds__(256) void prep_count(const float* __restrict__ W1,
                                                  const float* __restrict__ W2,
                                                  const float* __restrict__ Wp,
                                                  const int* __restrict__ src,
                                                  int E, int NB, int NBLK,
                                                  unsigned short* __restrict__ W1T,
                                                  unsigned short* __restrict__ Wcbf,
                                                  int* __restrict__ cnt) {
    __shared__ int lh[NBMAX];
    const int b = blockIdx.x, t = threadIdx.x;
    if (b < 64) {
        int o0 = b * 1024 + t * 4;
        unsigned short v[4];
        #pragma unroll
        for (int jj = 0; jj < 4; ++jj) {
            int o = o0 + jj;
            int j = o & 7, l = (o >> 3) & 63, kk = (o >> 9) & 3, n = (o >> 11) & 7, h = o >> 14;
            int row = h * 128 + kk * 32 + (l >> 4) * 8 + j;
            int col = n * 16 + (l & 15);
            v[jj] = f2bf(W1[(size_t)row * D + col]);
        }
        *reinterpret_cast<ushort4*>(&W1T[o0]) = make_ushort4(v[0], v[1], v[2], v[3]);
    } else if (b == 64) {
        #pragma unroll
        for (int i = 0; i < 8; ++i) {
            int idx = i * 256 + t;
            int col = idx >> 7, k = idx & 127;
            float acc = 0.f;
            if (col < 5) {
                #pragma unroll 8
                for (int j = 0; j < D; ++j) acc += W2[k * D + j] * Wp[j * 5 + col];
            }
            Wcbf[col * D + k] = f2bf(acc);
        }
    } else {
        const int blk = b - 65;
        for (int i = t; i < NB; i += 256) lh[i] = 0;
        __syncthreads();
        const int e0 = blk * CHUNK;
        const int e1 = min(e0 + CHUNK, E);
        for (int e = e0 + t; e < e1; e += 256) atomicAdd(&lh[src[e] >> BSHIFT], 1);
        __syncthreads();
        for (int k = t; k < NB; k += 256) cnt[k * NBLK + blk] = lh[k];
    }
}

// ---------------- K2: node transform (standalone, R6-proven) ----------------
__global__ __launch_bounds__(512) void node_kernel(const float* __restrict__ uf,
                                                   const float* __restrict__ vf,
                                                   const unsigned short* __restrict__ W1T,
                                                   int NU, int NM, int nbU,
                                                   unsigned short* __restrict__ Abf,
                                                   unsigned short* __restrict__ Bbf) {
    __shared__ unsigned short sW[16384];
    const int b = blockIdx.x, t = threadIdx.x;

    const float* feat;
    unsigned short* outp;
    int Nn, tile, h;
    if (b < nbU) { feat = uf; outp = Abf; Nn = NU; tile = b;       h = 0; }
    else         { feat = vf; outp = Bbf; Nn = NM; tile = b - nbU; h = 1; }
    const int r0 = tile * 256;

    {
        const uint4* srcp = reinterpret_cast<const uint4*>(W1T + (size_t)h * 16384);
        uint4* dstp = reinterpret_cast<uint4*>(sW);
        #pragma unroll
        for (int i = 0; i < 4; ++i) dstp[i * 512 + t] = srcp[i * 512 + t];
    }
    __syncthreads();

    const int wv = t >> 6, l = t & 63;
    const int m16 = l & 15, g4 = l >> 4;

    #pragma unroll
    for (int t16 = 0; t16 < 2; ++t16) {
        const int rowbase = r0 + wv * 32 + t16 * 16;
        if (rowbase >= Nn) break;
        const int arow = rowbase + m16;
        const bool rok = arow < Nn;
        const float* rp = feat + (size_t)(rok ? arow : 0) * D;

        union { bf16x8 v; unsigned short u[8]; } afr[4];
        #pragma unroll
        for (int kk = 0; kk < 4; ++kk) {
            int k0 = kk * 32 + g4 * 8;
            float4 f0 = make_float4(0.f, 0.f, 0.f, 0.f), f1 = f0;
            if (rok) {
                f0 = *reinterpret_cast<const float4*>(rp + k0);
                f1 = *reinterpret_cast<const float4*>(rp + k0 + 4);
            }
            afr[kk].u[0] = f2bf(f0.x); afr[kk].u[1] = f2bf(f0.y);
            afr[kk].u[2] = f2bf(f0.z); afr[kk].u[3] = f2bf(f0.w);
            afr[kk].u[4] = f2bf(f1.x); afr[kk].u[5] = f2bf(f1.y);
            afr[kk].u[6] = f2bf(f1.z); afr[kk].u[7] = f2bf(f1.w);
        }

        #pragma unroll
        for (int n = 0; n < 8; ++n) {
            f32x4 acc = (f32x4){0.f, 0.f, 0.f, 0.f};
            #pragma unroll
            for (int kk = 0; kk < 4; ++kk) {
                bf16x8 bfr = *reinterpret_cast<const bf16x8*>(&sW[((n * 4 + kk) * 64 + l) * 8]);
                acc = __builtin_amdgcn_mfma_f32_16x16x32_bf16(afr[kk].v, bfr, acc, 0, 0, 0);
            }
            #pragma unroll
            for (int r = 0; r < 4; ++r) {
                int row = rowbase + g4 * 4 + r;
                if (row < Nn) outp[(size_t)row * D + n * 16 + m16] = f2bf(acc[r]);
            }
        }
    }
}

// ---------------- K3a: per-bucket exclusive prefix over chunks (parallel) ----------------
__global__ __launch_bounds__(256) void scan_bucket(const int* __restrict__ cnt,
                                                   int NBLK,
                                                   int* __restrict__ basePB,
                                                   int* __restrict__ tot) {
    __shared__ int ls[256];
    const int k = blockIdx.x, t = threadIdx.x;
    int v = (t < NBLK) ? cnt[k * NBLK + t] : 0;
    ls[t] = v;
    __syncthreads();
    for (int off = 1; off < 256; off <<= 1) {
        int u = (t >= off) ? ls[t - off] : 0;
        __syncthreads();
        ls[t] += u;
        __syncthreads();
    }
    if (t < NBLK) basePB[k * NBLK + t] = ls[t] - v;   // exclusive within bucket
    if (t == 255) tot[k] = ls[255];
}

// ---------------- K3b: scan bucket totals -> start[k] (single tiny block) ----------------
__global__ __launch_bounds__(512) void scan_total(const int* __restrict__ tot,
                                                  int NB, int E,
                                                  int* __restrict__ start) {
    __shared__ int ps[512];
    const int t = threadIdx.x;
    const int k0 = 2 * t, k1 = 2 * t + 1;
    int a = (k0 < NB) ? tot[k0] : 0;
    int b = (k1 < NB) ? tot[k1] : 0;
    ps[t] = a + b;
    __syncthreads();
    for (int off = 1; off < 512; off <<= 1) {
        int u = (t >= off) ? ps[t - off] : 0;
        __syncthreads();
        ps[t] += u;
        __syncthreads();
    }
    int st = ps[t] - (a + b);
    if (k0 < NB) start[k0] = st;
    if (k1 < NB) start[k1] = st + a;
    if (t == 0) start[NB] = E;
}

// ---------------- K4: scatter with per-block LDS cursors (no global atomics) ----------------
__global__ __launch_bounds__(256) void sort_scatter(const int* __restrict__ src,
                                                    const int* __restrict__ dst,
                                                    int E, int NB, int NBLK,
                                                    const int* __restrict__ basePB,
                                                    const int* __restrict__ start,
                                                    uint2* __restrict__ sd,
                                                    int* __restrict__ eid) {
    __shared__ int cur[NBMAX];
    const int blk = blockIdx.x, t = threadIdx.x;
    for (int k = t; k < NB; k += 256) cur[k] = start[k] + basePB[k * NBLK + blk];
    __syncthreads();
    const int e0 = blk * CHUNK;
    const int e1 = min(e0 + CHUNK, E);
    for (int e = e0 + t; e < e1; e += 256) {
        int s = src[e];
        int d = dst[e];
        int pos = atomicAdd(&cur[s >> BSHIFT], 1);
        sd[pos] = make_uint2((unsigned)s, (unsigned)d);
        eid[pos] = e;
    }
}

// ---------------- K5: edge kernel, one block per bucket, A staged in swizzled LDS ----------------
__global__ __launch_bounds__(512) void edge_bucket(const unsigned short* __restrict__ A,
                                                   const unsigned short* __restrict__ B,
                                                   const uint2* __restrict__ sd,
                                                   const int* __restrict__ eid,
                                                   const unsigned short* __restrict__ Wcbf,
                                                   const int* __restrict__ start,
                                                   float* __restrict__ out,
                                                   int E, int NU) {
    __shared__ uint4 sA[BUCK * 16];   // 32KB, 16B-slot XOR swizzle
    const int k = blockIdx.x, t = threadIdx.x;
    const int rowbase = k << BSHIFT;

    #pragma unroll
    for (int i = t; i < BUCK * 16; i += 512) {
        int r = i >> 4, s = i & 15;
        uint4 v = (uint4){0u, 0u, 0u, 0u};
        if (rowbase + r < NU)
            v = *reinterpret_cast<const uint4*>(&A[(((size_t)(rowbase + r)) << 7) + s * 8]);
        sA[(r << 4) | (s ^ (r & 7))] = v;
    }

    const int l = t & 63, er = l & 15, quad = l >> 4, wv = t >> 6;
    bf16x8 wfrag[4];
    #pragma unroll
    for (int kk = 0; kk < 4; ++kk)
        wfrag[kk] = *reinterpret_cast<const bf16x8*>(&Wcbf[er * D + kk * 32 + quad * 8]);

    const int e0 = start[k];
    const int e1 = start[k + 1];
    __syncthreads();

    const int len = e1 - e0;
    if (len <= 0) return;
    const int G = (len + 15) >> 4;
    for (int g = wv; g < G; g += 8) {
        const int ebase = e0 + g * 16;
        const int ee = min(ebase + er, e1 - 1);
        uint2 sdv = sd[ee];
        const int rr = (int)sdv.x - rowbase;   // 0..BUCK-1

        uint4 av[4];
        #pragma unroll
        for (int kk = 0; kk < 4; ++kk)
            av[kk] = sA[(rr << 4) | (((kk << 2) | quad) ^ (rr & 7))];

        const unsigned short* bp = B + ((size_t)sdv.y << 7) + quad * 8;
        uint4 bv[4];
        #pragma unroll
        for (int kk = 0; kk < 4; ++kk)
            bv[kk] = *reinterpret_cast<const uint4*>(bp + kk * 32);

        const int eb = ebase + quad * 4;
        int evr[4];
        #pragma unroll
        for (int r = 0; r < 4; ++r) evr[r] = eid[min(eb + r, E - 1)];

        f32x4 acc = (f32x4){0.f, 0.f, 0.f, 0.f};
        #pragma unroll
        for (int kk = 0; kk < 4; ++kk) {
            unsigned int aw[4] = {av[kk].x, av[kk].y, av[kk].z, av[kk].w};
            unsigned int bw[4] = {bv[kk].x, bv[kk].y, bv[kk].z, bv[kk].w};
            union { bf16x8 v; unsigned short u[8]; } frag;
            #pragma unroll
            for (int pp = 0; pp < 4; ++pp) {
                f32x2 za = {bflo(aw[pp]), bfhi(aw[pp])};
                f32x2 zb = {bflo(bw[pp]), bfhi(bw[pp])};
                f32x2 gl = gelu2(za + zb);
                frag.u[2 * pp]     = f2bf(gl.x);
                frag.u[2 * pp + 1] = f2bf(gl.y);
            }
            acc = __builtin_amdgcn_mfma_f32_16x16x32_bf16(frag.v, wfrag[kk], acc, 0, 0, 0);
        }

        #pragma unroll
        for (int r = 0; r < 4; ++r) {
            int e = eb + r;
            if (er < 5 && e < e1) out[(size_t)evr[r] * 5 + er] = acc[r];
        }
    }
}

// ---------------- mid-tier edge (unsorted, R2-proven) ----------------
__global__ __launch_bounds__(256, 4) void edge_unsorted(const unsigned short* __restrict__ A,
                                                        const unsigned short* __restrict__ B,
                                                        const int* __restrict__ src,
                                                        const int* __restrict__ dst,
                                                        const unsigned short* __restrict__ Wcbf,
                                                        float* __restrict__ out, int E) {
    const int l    = threadIdx.x & 63;
    const int er   = l & 15;
    const int quad = l >> 4;
    const int wid  = blockIdx.x * 4 + (threadIdx.x >> 6);
    const int nw   = gridDim.x * 4;

    bf16x8 wfrag[4];
    #pragma unroll
    for (int kk = 0; kk < 4; ++kk)
        wfrag[kk] = *reinterpret_cast<const bf16x8*>(&Wcbf[er * D + kk * 32 + quad * 8]);

    const int P = (E + 31) >> 5;
    if (wid >= P) return;
    const int Emax = E - 1;

    int ia = wid * 32 + er, ib = ia + 16;
    int sa = src[min(ia, Emax)], da = dst[min(ia, Emax)];
    int sb = src[min(ib, Emax)], db = dst[min(ib, Emax)];

    for (int p = wid; p < P; p += nw) {
        int pn = p + nw;
        int pc = pn < P ? pn : p;
        int ja = pc * 32 + er, jb = ja + 16;
        int san = src[min(ja, Emax)], dan = dst[min(ja, Emax)];
        int sbn = src[min(jb, Emax)], dbn = dst[min(jb, Emax)];

        const unsigned short* apA = A + ((size_t)sa << 7) + quad * 8;
        const unsigned short* bpA = B + ((size_t)da << 7) + quad * 8;
        const unsigned short* apB = A + ((size_t)sb << 7) + quad * 8;
        const unsigned short* bpB = B + ((size_t)db << 7) + quad * 8;
        uint4 a0[4], b0[4], a1[4], b1[4];
        #pragma unroll
        for (int kk = 0; kk < 4; ++kk) {
            a0[kk] = *reinterpret_cast<const uint4*>(apA + kk * 32);
            b0[kk] = *reinterpret_cast<const uint4*>(bpA + kk * 32);
            a1[kk] = *reinterpret_cast<const uint4*>(apB + kk * 32);
            b1[kk] = *reinterpret_cast<const uint4*>(bpB + kk * 32);
        }

        f32x4 accA = (f32x4){0.f, 0.f, 0.f, 0.f};
        f32x4 accB = accA;
        #pragma unroll
        for (int kk = 0; kk < 4; ++kk) {
            unsigned int aw[4] = {a0[kk].x, a0[kk].y, a0[kk].z, a0[kk].w};
            unsigned int bw[4] = {b0[kk].x, b0[kk].y, b0[kk].z, b0[kk].w};
            union { bf16x8 v; unsigned short u[8]; } frag;
            #pragma unroll
            for (int pp = 0; pp < 4; ++pp) {
                f32x2 za = {bflo(aw[pp]), bfhi(aw[pp])};
                f32x2 zb = {bflo(bw[pp]), bfhi(bw[pp])};
                f32x2 g = gelu2(za + zb);
                frag.u[2 * pp]     = f2bf(g.x);
                frag.u[2 * pp + 1] = f2bf(g.y);
            }
            accA = __builtin_amdgcn_mfma_f32_16x16x32_bf16(frag.v, wfrag[kk], accA, 0, 0, 0);
        }
        #pragma unroll
        for (int kk = 0; kk < 4; ++kk) {
            unsigned int aw[4] = {a1[kk].x, a1[kk].y, a1[kk].z, a1[kk].w};
            unsigned int bw[4] = {b1[kk].x, b1[kk].y, b1[kk].z, b1[kk].w};
            union { bf16x8 v; unsigned short u[8]; } frag;
            #pragma unroll
            for (int pp = 0; pp < 4; ++pp) {
                f32x2 za = {bflo(aw[pp]), bfhi(aw[pp])};
                f32x2 zb = {bflo(bw[pp]), bfhi(bw[pp])};
                f32x2 g = gelu2(za + zb);
                frag.u[2 * pp]     = f2bf(g.x);
                frag.u[2 * pp + 1] = f2bf(g.y);
            }
            accB = __builtin_amdgcn_mfma_f32_16x16x32_bf16(frag.v, wfrag[kk], accB, 0, 0, 0);
        }

        int e0 = p << 5;
        #pragma unroll
        for (int r = 0; r < 4; ++r) {
            int eA = e0 + quad * 4 + r;
            if (er < 5 && eA < E) out[(size_t)eA * 5 + er] = accA[r];
        }
        #pragma unroll
        for (int r = 0; r < 4; ++r) {
            int eB = e0 + 16 + quad * 4 + r;
            if (er < 5 && eB < E) out[(size_t)eB * 5 + er] = accB[r];
        }
        sa = san; da = dan; sb = sbn; db = dbn;
    }
}

// ---------------- fallback (ws too small): fully fused per-edge ----------------
__global__ __launch_bounds__(256) void fused_fallback(const float* __restrict__ uf,
                                                      const float* __restrict__ vf,
                                                      const int* __restrict__ src,
                                                      const int* __restrict__ dst,
                                                      const float* __restrict__ W1,
                                                      const float* __restrict__ W2,
                                                      const float* __restrict__ Wp,
                                                      float* __restrict__ out, int E) {
    __shared__ unsigned short sW[256 * 128];
    __shared__ float sWc[5 * 128];
    __shared__ float sH[4][256];
    const int t = threadIdx.x;
    #pragma unroll
    for (int i = 0; i < 32; ++i) {
        int f = (i * 256 + t) * 4;
        float4 v = *reinterpret_cast<const float4*>(&W1[f]);
        sW[f + 0] = f2bf(v.x); sW[f + 1] = f2bf(v.y);
        sW[f + 2] = f2bf(v.z); sW[f + 3] = f2bf(v.w);
    }
    for (int idx = t; idx < 640; idx += 256) {
        int c = idx >> 7, k = idx & 127;
        float a = 0.f;
        for (int m = 0; m < 128; ++m) a += W2[k * 128 + m] * Wp[m * 5 + c];
        sWc[c * 128 + k] = a;
    }
    __syncthreads();
    const int wid = t >> 6, l = t & 63;
    const int nw = gridDim.x * 4;
    for (int e = blockIdx.x * 4 + wid; e < E; e += nw) {
        int s = src[e], d0 = dst[e];
        float2 hu = *reinterpret_cast<const float2*>(&uf[(size_t)s * 128 + 2 * l]);
        float2 hv = *reinterpret_cast<const float2*>(&vf[(size_t)d0 * 128 + 2 * l]);
        sH[wid][2 * l] = hu.x; sH[wid][2 * l + 1] = hu.y;
        sH[wid][128 + 2 * l] = hv.x; sH[wid][128 + 2 * l + 1] = hv.y;
        __builtin_amdgcn_wave_barrier();
        float z0 = 0.f, z1 = 0.f;
        for (int k = 0; k < 256; ++k) {
            float h = sH[wid][k];
            z0 += h * __uint_as_float((unsigned int)sW[k * 128 + l] << 16);
            z1 += h * __uint_as_float((unsigned int)sW[k * 128 + l + 64] << 16);
        }
        float g0 = gelu_erf(z0), g1 = gelu_erf(z1);
        float acc[5];
        #pragma unroll
        for (int c = 0; c < 5; ++c)
            acc[c] = g0 * sWc[c * 128 + l] + g1 * sWc[c * 128 + l + 64];
        #pragma unroll
        for (int c = 0; c < 5; ++c) {
            float v = acc[c];
            v += __shfl_xor(v, 1);  v += __shfl_xor(v, 2);
            v += __shfl_xor(v, 4);  v += __shfl_xor(v, 8);
            v += __shfl_xor(v, 16); v += __shfl_xor(v, 32);
            acc[c] = v;
        }
        float v = acc[0];
        if (l == 1) v = acc[1];
        if (l == 2) v = acc[2];
        if (l == 3) v = acc[3];
        if (l == 4) v = acc[4];
        if (l < 5) out[(size_t)e * 5 + l] = v;
        __builtin_amdgcn_wave_barrier();
    }
}

extern "C" void kernel_launch(void* const* d_in, const int* in_sizes, int n_in,
                              void* d_out, int out_size, void* d_ws, size_t ws_size,
                              hipStream_t stream) {
    const float* ufeat = (const float*)d_in[0];
    const float* ifeat = (const float*)d_in[1];
    const int*   src   = (const int*)d_in[2];
    const int*   dst   = (const int*)d_in[3];
    const float* W1    = (const float*)d_in[4];
    const float* W2    = (const float*)d_in[5];
    const float* Wp    = (const float*)d_in[6];
    float* out = (float*)d_out;

    const int NU = in_sizes[0] / D;
    const int NM = in_sizes[1] / D;
    const int E  = in_sizes[2];
    const int NB   = (NU + BUCK - 1) >> BSHIFT;
    const int NBLK = (E + CHUNK - 1) / CHUNK;

    size_t cur = 0;
    auto alloc = [&](size_t bytes) { size_t o = cur; cur = (cur + bytes + 255) & ~(size_t)255; return o; };
    size_t off_Wc    = alloc(4096);
    size_t off_W1T   = alloc(65536);
    size_t off_A     = alloc((size_t)NU * D * 2);
    size_t off_B     = alloc((size_t)NM * D * 2);
    size_t need_mid  = cur;
    size_t off_cnt   = alloc((size_t)NB * NBLK * 4);
    size_t off_bpb   = alloc((size_t)NB * NBLK * 4);
    size_t off_tot   = alloc((size_t)NB * 4);
    size_t off_start = alloc((size_t)(NB + 1) * 4);
    size_t off_sd    = alloc((size_t)E * 8);
    size_t off_eid   = alloc((size_t)E * 4);
    size_t need_full = cur;

    if (ws_size >= need_mid) {
        unsigned short* Wcbf = (unsigned short*)((char*)d_ws + off_Wc);
        unsigned short* W1T  = (unsigned short*)((char*)d_ws + off_W1T);
        unsigned short* Abf  = (unsigned short*)((char*)d_ws + off_A);
        unsigned short* Bbf  = (unsigned short*)((char*)d_ws + off_B);
        int nbU = (NU + 255) / 256, nbM = (NM + 255) / 256;

        if (ws_size >= need_full && NB >= 2 && NB <= NBMAX && NBLK <= 256) {
            int*   cnt   = (int*)((char*)d_ws + off_cnt);
            int*   bpb   = (int*)((char*)d_ws + off_bpb);
            int*   tot   = (int*)((char*)d_ws + off_tot);
            int*   start = (int*)((char*)d_ws + off_start);
            uint2* sd    = (uint2*)((char*)d_ws + off_sd);
            int*   eid   = (int*)((char*)d_ws + off_eid);

            prep_count<<<dim3(65 + NBLK), dim3(256), 0, stream>>>(W1, W2, Wp, src, E, NB, NBLK,
                                                                  W1T, Wcbf, cnt);
            node_kernel<<<dim3(nbU + nbM), dim3(512), 0, stream>>>(ufeat, ifeat, W1T, NU, NM,
                                                                   nbU, Abf, Bbf);
            scan_bucket<<<dim3(NB), dim3(256), 0, stream>>>(cnt, NBLK, bpb, tot);
            scan_total<<<dim3(1), dim3(512), 0, stream>>>(tot, NB, E, start);
            sort_scatter<<<dim3(NBLK), dim3(256), 0, stream>>>(src, dst, E, NB, NBLK,
                                                               bpb, start, sd, eid);
            edge_bucket<<<dim3(NB), dim3(512), 0, stream>>>(Abf, Bbf, sd, eid, Wcbf, start,
                                                            out, E, NU);
        } else {
            prep_count<<<dim3(65), dim3(256), 0, stream>>>(W1, W2, Wp, src, E, NB, NBLK,
                                                           W1T, Wcbf, (int*)((char*)d_ws + off_Wc));
            node_kernel<<<dim3(nbU + nbM), dim3(512), 0, stream>>>(ufeat, ifeat, W1T, NU, NM,
                                                                   nbU, Abf, Bbf);
            edge_unsorted<<<dim3(2048), dim3(256), 0, stream>>>(Abf, Bbf, src, dst, Wcbf, out, E);
        }
    } else {
        fused_fallback<<<dim3(4096), dim3(256), 0, stream>>>(ufeat, ifeat, src, dst,
                                                             W1, W2, Wp, out, E);
    }
}

// Round 9
// 109.009 us; speedup vs baseline: 3.9437x; 1.4977x over previous
//
#include <hip/hip_runtime.h>
#include <hip/hip_bf16.h>

#define D 128

typedef short bf16x8 __attribute__((ext_vector_type(8)));
typedef float f32x4 __attribute__((ext_vector_type(4)));
typedef float f32x2 __attribute__((ext_vector_type(2)));

__device__ __forceinline__ unsigned short f2bf(float x) {
    __hip_bfloat16 h = __float2bfloat16(x);
    return *reinterpret_cast<unsigned short*>(&h);
}
__device__ __forceinline__ float bflo(unsigned int w) { return __uint_as_float(w << 16); }
__device__ __forceinline__ float bfhi(unsigned int w) { return __uint_as_float(w & 0xffff0000u); }

// tanh-form GELU pair: gelu(z) = z - z/(1+q), q = exp2(z*(2.3022646 + 0.1029466 z^2))
// Overflow-safe (q=inf -> rcp=0 -> gelu=z). |err vs exact erf-GELU| ~5e-4.
__device__ __forceinline__ f32x2 gelu2(f32x2 z) {
    f32x2 z2 = z * z;
    f32x2 c1 = {0.1029466f, 0.1029466f};
    f32x2 c0 = {2.3022646f, 2.3022646f};
    f32x2 xe = z * __builtin_elementwise_fma(z2, c1, c0);
    f32x2 q;
    q.x = __builtin_amdgcn_exp2f(xe.x);
    q.y = __builtin_amdgcn_exp2f(xe.y);
    f32x2 d = q + 1.0f;
    f32x2 r;
    r.x = __builtin_amdgcn_rcpf(d.x);
    r.y = __builtin_amdgcn_rcpf(d.y);
    return __builtin_elementwise_fma(-z, r, z);
}

__device__ __forceinline__ float gelu_erf(float z) {
    float y = fabsf(z) * 0.70710678118654752f;
    float t = __builtin_amdgcn_rcpf(1.0f + 0.3275911f * y);
    float poly = ((((1.061405429f * t - 1.453152027f) * t + 1.421413741f) * t
                   - 0.284496736f) * t + 0.254829592f) * t;
    float e = __expf(-y * y);
    float erfv = 1.0f - poly * e;
    erfv = copysignf(erfv, z);
    return 0.5f * z * (1.0f + erfv);
}

// ---------------- K1: W1T in MFMA-fragment order + Wc ----------------
// Flat ushort index o = h*16384 + n*2048 + kk*512 + l*8 + j  maps to
//   W1[h*128 + kk*32 + (l>>4)*8 + j][n*16 + (l&15)]
__global__ __launch_bounds__(256) void prep0_kernel(const float* __restrict__ W1,
                                                    const float* __restrict__ W2,
                                                    const float* __restrict__ Wp,
                                                    unsigned short* __restrict__ W1T,
                                                    unsigned short* __restrict__ Wcbf) {
    const int b = blockIdx.x, t = threadIdx.x;
    if (b < 64) {
        int o0 = b * 1024 + t * 4;
        unsigned short v[4];
        #pragma unroll
        for (int jj = 0; jj < 4; ++jj) {
            int o = o0 + jj;
            int j = o & 7, l = (o >> 3) & 63, kk = (o >> 9) & 3, n = (o >> 11) & 7, h = o >> 14;
            int row = h * 128 + kk * 32 + (l >> 4) * 8 + j;
            int col = n * 16 + (l & 15);
            v[jj] = f2bf(W1[(size_t)row * D + col]);
        }
        *reinterpret_cast<ushort4*>(&W1T[o0]) = make_ushort4(v[0], v[1], v[2], v[3]);
    } else {
        #pragma unroll
        for (int i = 0; i < 8; ++i) {
            int idx = i * 256 + t;
            int col = idx >> 7, k = idx & 127;
            float acc = 0.f;
            if (col < 5) {
                #pragma unroll 8
                for (int j = 0; j < D; ++j) acc += W2[k * D + j] * Wp[j * 5 + col];
            }
            Wcbf[col * D + k] = f2bf(acc);
        }
    }
}

// ---------------- K2: node transform, swapped operands -> 8B packed stores ----------------
// mfma(A=W-frag, B=feat-frag): D[m=Wcol][n=featrow]; lane (m16,g4) holds
// feat-row rowbase+m16, W-cols nblk*16 + g4*4 + r  -> 4 consecutive bf16 = one 8B store.
__global__ __launch_bounds__(512) void node_kernel(const float* __restrict__ uf,
                                                   const float* __restrict__ vf,
                                                   const unsigned short* __restrict__ W1T,
                                                   int NU, int NM, int nbU,
                                                   unsigned short* __restrict__ Abf,
                                                   unsigned short* __restrict__ Bbf) {
    __shared__ unsigned short sW[16384];
    const int b = blockIdx.x, t = threadIdx.x;

    const float* feat;
    unsigned short* outp;
    int Nn, tile, h;
    if (b < nbU) { feat = uf; outp = Abf; Nn = NU; tile = b;       h = 0; }
    else         { feat = vf; outp = Bbf; Nn = NM; tile = b - nbU; h = 1; }
    const int r0 = tile * 256;

    {
        const uint4* srcp = reinterpret_cast<const uint4*>(W1T + (size_t)h * 16384);
        uint4* dstp = reinterpret_cast<uint4*>(sW);
        #pragma unroll
        for (int i = 0; i < 4; ++i) dstp[i * 512 + t] = srcp[i * 512 + t];
    }
    __syncthreads();

    const int wv = t >> 6, l = t & 63;
    const int m16 = l & 15, g4 = l >> 4;

    #pragma unroll
    for (int t16 = 0; t16 < 2; ++t16) {
        const int rowbase = r0 + wv * 32 + t16 * 16;
        if (rowbase >= Nn) break;
        const int arow = rowbase + m16;
        const bool rok = arow < Nn;
        const float* rp = feat + (size_t)(rok ? arow : 0) * D;

        union { bf16x8 v; unsigned short u[8]; } afr[4];
        #pragma unroll
        for (int kk = 0; kk < 4; ++kk) {
            int k0 = kk * 32 + g4 * 8;
            float4 f0 = make_float4(0.f, 0.f, 0.f, 0.f), f1 = f0;
            if (rok) {
                f0 = *reinterpret_cast<const float4*>(rp + k0);
                f1 = *reinterpret_cast<const float4*>(rp + k0 + 4);
            }
            afr[kk].u[0] = f2bf(f0.x); afr[kk].u[1] = f2bf(f0.y);
            afr[kk].u[2] = f2bf(f0.z); afr[kk].u[3] = f2bf(f0.w);
            afr[kk].u[4] = f2bf(f1.x); afr[kk].u[5] = f2bf(f1.y);
            afr[kk].u[6] = f2bf(f1.z); afr[kk].u[7] = f2bf(f1.w);
        }

        #pragma unroll
        for (int n = 0; n < 8; ++n) {
            f32x4 acc = (f32x4){0.f, 0.f, 0.f, 0.f};
            #pragma unroll
            for (int kk = 0; kk < 4; ++kk) {
                bf16x8 bfr = *reinterpret_cast<const bf16x8*>(&sW[((n * 4 + kk) * 64 + l) * 8]);
                acc = __builtin_amdgcn_mfma_f32_16x16x32_bf16(bfr, afr[kk].v, acc, 0, 0, 0);
            }
            unsigned int lo = (unsigned int)f2bf(acc[0]) | ((unsigned int)f2bf(acc[1]) << 16);
            unsigned int hi = (unsigned int)f2bf(acc[2]) | ((unsigned int)f2bf(acc[3]) << 16);
            if (rok)
                *reinterpret_cast<uint2*>(&outp[(size_t)arow * D + n * 16 + g4 * 4]) =
                    make_uint2(lo, hi);
        }
    }
}

// ---------------- K3: edge kernel, fast path (E % 16 == 0) ----------------
__device__ __forceinline__ void issue8(const unsigned short* __restrict__ A,
                                       const unsigned short* __restrict__ B,
                                       int s, int d, int quad, uint4* av, uint4* bv) {
    const unsigned short* ap = A + ((size_t)s << 7) + quad * 8;
    const unsigned short* bp = B + ((size_t)d << 7) + quad * 8;
    #pragma unroll
    for (int kk = 0; kk < 4; ++kk) {
        av[kk] = *reinterpret_cast<const uint4*>(ap + kk * 32);
        bv[kk] = *reinterpret_cast<const uint4*>(bp + kk * 32);
    }
}

__device__ __forceinline__ void edge_compute(const uint4* av, const uint4* bv,
                                             const bf16x8* wfrag, float* __restrict__ out,
                                             int g, int er, int quad) {
    f32x4 acc = (f32x4){0.f, 0.f, 0.f, 0.f};
    #pragma unroll
    for (int kk = 0; kk < 4; ++kk) {
        const unsigned int aw[4] = {av[kk].x, av[kk].y, av[kk].z, av[kk].w};
        const unsigned int bw[4] = {bv[kk].x, bv[kk].y, bv[kk].z, bv[kk].w};
        union { unsigned int w[4]; bf16x8 v; } frag;
        #pragma unroll
        for (int pp = 0; pp < 4; ++pp) {
            f32x2 za = {bflo(aw[pp]), bfhi(aw[pp])};
            f32x2 zb = {bflo(bw[pp]), bfhi(bw[pp])};
            f32x2 gl = gelu2(za + zb);
            // pack two f32 -> two bf16 (truncate) in ONE v_perm_b32
            frag.w[pp] = __builtin_amdgcn_perm(__float_as_uint(gl.y),
                                               __float_as_uint(gl.x), 0x07060302u);
        }
        acc = __builtin_amdgcn_mfma_f32_16x16x32_bf16(frag.v, wfrag[kk], acc, 0, 0, 0);
    }
    const long eb = (long)g * 16 + quad * 4;
    if (er < 5) {
        #pragma unroll
        for (int r = 0; r < 4; ++r) out[(eb + r) * 5 + er] = acc[r];
    }
}

__global__ __launch_bounds__(256, 4) void edge_fast(const unsigned short* __restrict__ A,
                                                    const unsigned short* __restrict__ B,
                                                    const int* __restrict__ src,
                                                    const int* __restrict__ dst,
                                                    const unsigned short* __restrict__ Wcbf,
                                                    float* __restrict__ out, int G) {
    const int l = threadIdx.x & 63, er = l & 15, quad = l >> 4;
    const int wid = blockIdx.x * 4 + (threadIdx.x >> 6);
    const int NW = gridDim.x * 4;
    const int q = G / NW, rr = G % NW;
    const int count = q + (wid < rr ? 1 : 0);
    if (count == 0) return;
    const int g0 = wid * q + (wid < rr ? wid : rr);
    const int glast = g0 + count - 1;

    bf16x8 wfrag[4];
    #pragma unroll
    for (int kk = 0; kk < 4; ++kk)
        wfrag[kk] = *reinterpret_cast<const bf16x8*>(&Wcbf[er * D + kk * 32 + quad * 8]);

    uint4 aA[4], bA[4], aB[4], bB[4];
    {   // prologue: gathers for g0 into buf A; prefetch idx for g0+1
        int s = src[g0 * 16 + er], d = dst[g0 * 16 + er];
        issue8(A, B, s, d, quad, aA, bA);
    }
    int gN = (count > 1) ? g0 + 1 : g0;
    int sN = src[gN * 16 + er], dN = dst[gN * 16 + er];

    int i = 0;
    while (true) {
        // fill buf B with group g0+i+1 (clamped); prefetch idx for g0+i+2
        issue8(A, B, sN, dN, quad, aB, bB);
        {
            int g2 = g0 + i + 2; if (g2 > glast) g2 = glast;
            sN = src[g2 * 16 + er]; dN = dst[g2 * 16 + er];
        }
        __builtin_amdgcn_sched_barrier(0);   // keep the loads above the compute
        edge_compute(aA, bA, wfrag, out, g0 + i, er, quad);
        if (++i >= count) break;

        issue8(A, B, sN, dN, quad, aA, bA);
        {
            int g2 = g0 + i + 2; if (g2 > glast) g2 = glast;
            sN = src[g2 * 16 + er]; dN = dst[g2 * 16 + er];
        }
        __builtin_amdgcn_sched_barrier(0);
        edge_compute(aB, bB, wfrag, out, g0 + i, er, quad);
        if (++i >= count) break;
    }
}

// ---------------- generic edge (any E), R2-proven ----------------
__global__ __launch_bounds__(256, 4) void edge_unsorted(const unsigned short* __restrict__ A,
                                                        const unsigned short* __restrict__ B,
                                                        const int* __restrict__ src,
                                                        const int* __restrict__ dst,
                                                        const unsigned short* __restrict__ Wcbf,
                                                        float* __restrict__ out, int E) {
    const int l    = threadIdx.x & 63;
    const int er   = l & 15;
    const int quad = l >> 4;
    const int wid  = blockIdx.x * 4 + (threadIdx.x >> 6);
    const int nw   = gridDim.x * 4;

    bf16x8 wfrag[4];
    #pragma unroll
    for (int kk = 0; kk < 4; ++kk)
        wfrag[kk] = *reinterpret_cast<const bf16x8*>(&Wcbf[er * D + kk * 32 + quad * 8]);

    const int P = (E + 15) >> 4;
    const int Emax = E - 1;
    for (int p = wid; p < P; p += nw) {
        int ia = p * 16 + er;
        int s = src[min(ia, Emax)], d = dst[min(ia, Emax)];
        uint4 av[4], bv[4];
        issue8(A, B, s, d, quad, av, bv);

        f32x4 acc = (f32x4){0.f, 0.f, 0.f, 0.f};
        #pragma unroll
        for (int kk = 0; kk < 4; ++kk) {
            const unsigned int aw[4] = {av[kk].x, av[kk].y, av[kk].z, av[kk].w};
            const unsigned int bw[4] = {bv[kk].x, bv[kk].y, bv[kk].z, bv[kk].w};
            union { unsigned int w[4]; bf16x8 v; } frag;
            #pragma unroll
            for (int pp = 0; pp < 4; ++pp) {
                f32x2 za = {bflo(aw[pp]), bfhi(aw[pp])};
                f32x2 zb = {bflo(bw[pp]), bfhi(bw[pp])};
                f32x2 gl = gelu2(za + zb);
                frag.w[pp] = __builtin_amdgcn_perm(__float_as_uint(gl.y),
                                                   __float_as_uint(gl.x), 0x07060302u);
            }
            acc = __builtin_amdgcn_mfma_f32_16x16x32_bf16(frag.v, wfrag[kk], acc, 0, 0, 0);
        }
        #pragma unroll
        for (int r = 0; r < 4; ++r) {
            int e = p * 16 + quad * 4 + r;
            if (er < 5 && e < E) out[(size_t)e * 5 + er] = acc[r];
        }
    }
}

// ---------------- fallback (ws too small): fully fused per-edge ----------------
__global__ __launch_bounds__(256) void fused_fallback(const float* __restrict__ uf,
                                                      const float* __restrict__ vf,
                                                      const int* __restrict__ src,
                                                      const int* __restrict__ dst,
                                                      const float* __restrict__ W1,
                                                      const float* __restrict__ W2,
                                                      const float* __restrict__ Wp,
                                                      float* __restrict__ out, int E) {
    __shared__ unsigned short sW[256 * 128];
    __shared__ float sWc[5 * 128];
    __shared__ float sH[4][256];
    const int t = threadIdx.x;
    #pragma unroll
    for (int i = 0; i < 32; ++i) {
        int f = (i * 256 + t) * 4;
        float4 v = *reinterpret_cast<const float4*>(&W1[f]);
        sW[f + 0] = f2bf(v.x); sW[f + 1] = f2bf(v.y);
        sW[f + 2] = f2bf(v.z); sW[f + 3] = f2bf(v.w);
    }
    for (int idx = t; idx < 640; idx += 256) {
        int c = idx >> 7, k = idx & 127;
        float a = 0.f;
        for (int m = 0; m < 128; ++m) a += W2[k * 128 + m] * Wp[m * 5 + c];
        sWc[c * 128 + k] = a;
    }
    __syncthreads();
    const int wid = t >> 6, l = t & 63;
    const int nw = gridDim.x * 4;
    for (int e = blockIdx.x * 4 + wid; e < E; e += nw) {
        int s = src[e], d0 = dst[e];
        float2 hu = *reinterpret_cast<const float2*>(&uf[(size_t)s * 128 + 2 * l]);
        float2 hv = *reinterpret_cast<const float2*>(&vf[(size_t)d0 * 128 + 2 * l]);
        sH[wid][2 * l] = hu.x; sH[wid][2 * l + 1] = hu.y;
        sH[wid][128 + 2 * l] = hv.x; sH[wid][128 + 2 * l + 1] = hv.y;
        __builtin_amdgcn_wave_barrier();
        float z0 = 0.f, z1 = 0.f;
        for (int k = 0; k < 256; ++k) {
            float h = sH[wid][k];
            z0 += h * __uint_as_float((unsigned int)sW[k * 128 + l] << 16);
            z1 += h * __uint_as_float((unsigned int)sW[k * 128 + l + 64] << 16);
        }
        float g0 = gelu_erf(z0), g1 = gelu_erf(z1);
        float acc[5];
        #pragma unroll
        for (int c = 0; c < 5; ++c)
            acc[c] = g0 * sWc[c * 128 + l] + g1 * sWc[c * 128 + l + 64];
        #pragma unroll
        for (int c = 0; c < 5; ++c) {
            float v = acc[c];
            v += __shfl_xor(v, 1);  v += __shfl_xor(v, 2);
            v += __shfl_xor(v, 4);  v += __shfl_xor(v, 8);
            v += __shfl_xor(v, 16); v += __shfl_xor(v, 32);
            acc[c] = v;
        }
        float v = acc[0];
        if (l == 1) v = acc[1];
        if (l == 2) v = acc[2];
        if (l == 3) v = acc[3];
        if (l == 4) v = acc[4];
        if (l < 5) out[(size_t)e * 5 + l] = v;
        __builtin_amdgcn_wave_barrier();
    }
}

extern "C" void kernel_launch(void* const* d_in, const int* in_sizes, int n_in,
                              void* d_out, int out_size, void* d_ws, size_t ws_size,
                              hipStream_t stream) {
    const float* ufeat = (const float*)d_in[0];
    const float* ifeat = (const float*)d_in[1];
    const int*   src   = (const int*)d_in[2];
    const int*   dst   = (const int*)d_in[3];
    const float* W1    = (const float*)d_in[4];
    const float* W2    = (const float*)d_in[5];
    const float* Wp    = (const float*)d_in[6];
    float* out = (float*)d_out;

    const int NU = in_sizes[0] / D;
    const int NM = in_sizes[1] / D;
    const int E  = in_sizes[2];

    size_t cur = 0;
    auto alloc = [&](size_t bytes) { size_t o = cur; cur = (cur + bytes + 255) & ~(size_t)255; return o; };
    size_t off_Wc  = alloc(4096);
    size_t off_W1T = alloc(65536);
    size_t off_A   = alloc((size_t)NU * D * 2);
    size_t off_B   = alloc((size_t)NM * D * 2);
    size_t need    = cur;

    if (ws_size >= need) {
        unsigned short* Wcbf = (unsigned short*)((char*)d_ws + off_Wc);
        unsigned short* W1T  = (unsigned short*)((char*)d_ws + off_W1T);
        unsigned short* Abf  = (unsigned short*)((char*)d_ws + off_A);
        unsigned short* Bbf  = (unsigned short*)((char*)d_ws + off_B);
        int nbU = (NU + 255) / 256, nbM = (NM + 255) / 256;

        prep0_kernel<<<dim3(65), dim3(256), 0, stream>>>(W1, W2, Wp, W1T, Wcbf);
        node_kernel<<<dim3(nbU + nbM), dim3(512), 0, stream>>>(ufeat, ifeat, W1T, NU, NM,
                                                               nbU, Abf, Bbf);
        if ((E & 15) == 0 && E >= 16) {
            edge_fast<<<dim3(1024), dim3(256), 0, stream>>>(Abf, Bbf, src, dst, Wcbf,
                                                            out, E >> 4);
        } else {
            edge_unsorted<<<dim3(2048), dim3(256), 0, stream>>>(Abf, Bbf, src, dst, Wcbf, out, E);
        }
    } else {
        fused_fallback<<<dim3(4096), dim3(256), 0, stream>>>(ufeat, ifeat, src, dst,
                                                             W1, W2, Wp, out, E);
    }
}

// Round 10
// 99.567 us; speedup vs baseline: 4.3177x; 1.0948x over previous
//
#include <hip/hip_runtime.h>
#include <hip/hip_bf16.h>

#define D 128

typedef short bf16x8 __attribute__((ext_vector_type(8)));
typedef float f32x4 __attribute__((ext_vector_type(4)));
typedef float f32x2 __attribute__((ext_vector_type(2)));

__device__ __forceinline__ unsigned short f2bf(float x) {
    __hip_bfloat16 h = __float2bfloat16(x);
    return *reinterpret_cast<unsigned short*>(&h);
}
__device__ __forceinline__ float bflo(unsigned int w) { return __uint_as_float(w << 16); }
__device__ __forceinline__ float bfhi(unsigned int w) { return __uint_as_float(w & 0xffff0000u); }

// tanh-form GELU pair: gelu(z) = z - z/(1+q), q = exp2(z*(2.3022646 + 0.1029466 z^2))
// Overflow-safe (q=inf -> rcp=0 -> gelu=z). |err vs exact erf-GELU| ~5e-4.
__device__ __forceinline__ f32x2 gelu2(f32x2 z) {
    f32x2 z2 = z * z;
    f32x2 c1 = {0.1029466f, 0.1029466f};
    f32x2 c0 = {2.3022646f, 2.3022646f};
    f32x2 xe = z * __builtin_elementwise_fma(z2, c1, c0);
    f32x2 q;
    q.x = __builtin_amdgcn_exp2f(xe.x);
    q.y = __builtin_amdgcn_exp2f(xe.y);
    f32x2 d = q + 1.0f;
    f32x2 r;
    r.x = __builtin_amdgcn_rcpf(d.x);
    r.y = __builtin_amdgcn_rcpf(d.y);
    return __builtin_elementwise_fma(-z, r, z);
}

__device__ __forceinline__ float gelu_erf(float z) {
    float y = fabsf(z) * 0.70710678118654752f;
    float t = __builtin_amdgcn_rcpf(1.0f + 0.3275911f * y);
    float poly = ((((1.061405429f * t - 1.453152027f) * t + 1.421413741f) * t
                   - 0.284496736f) * t + 0.254829592f) * t;
    float e = __expf(-y * y);
    float erfv = 1.0f - poly * e;
    erfv = copysignf(erfv, z);
    return 0.5f * z * (1.0f + erfv);
}

// ---------------- K1: fused node transform + in-block W1 transpose + Wc ----------------
// sW fragment order: sW[((n*4+kk)*64 + l)*8 + j] = bf16( W1[h*128 + kk*32 + (l>>4)*8 + j][n*16 + (l&15)] )
// mfma(A=W-frag, B=feat-frag): lane (m16,g4) holds feat-row rowbase+m16,
// W-cols n*16 + g4*4 + r -> 4 consecutive bf16 = one 8B store.
__global__ __launch_bounds__(512) void node_wc(const float* __restrict__ uf,
                                               const float* __restrict__ vf,
                                               const float* __restrict__ W1,
                                               const float* __restrict__ W2,
                                               const float* __restrict__ Wp,
                                               int NU, int NM, int nbU, int nbM,
                                               unsigned short* __restrict__ Abf,
                                               unsigned short* __restrict__ Bbf,
                                               unsigned short* __restrict__ Wcbf) {
    const int b = blockIdx.x, t = threadIdx.x;

    if (b == nbU + nbM) {
        // Wc block: Wcbf[col][k] = bf16(sum_j W2[k][j] Wp[j][col]), cols 5..15 zero
        for (int idx = t; idx < 2048; idx += 512) {
            int col = idx >> 7, k = idx & 127;
            float acc = 0.f;
            if (col < 5) {
                #pragma unroll 8
                for (int j = 0; j < D; ++j) acc += W2[k * D + j] * Wp[j * 5 + col];
            }
            Wcbf[col * D + k] = f2bf(acc);
        }
        return;
    }

    __shared__ unsigned short sW[16384];
    const float* feat;
    unsigned short* outp;
    int Nn, tile, h;
    if (b < nbU) { feat = uf; outp = Abf; Nn = NU; tile = b;       h = 0; }
    else         { feat = vf; outp = Bbf; Nn = NM; tile = b - nbU; h = 1; }
    const int r0 = tile * 256;

    // stage W1 half into LDS in fragment order (scattered reads, L2-hot after first blocks)
    #pragma unroll
    for (int i = 0; i < 8; ++i) {
        int o0 = (i * 512 + t) * 4;
        unsigned short v[4];
        #pragma unroll
        for (int jj = 0; jj < 4; ++jj) {
            int o = o0 + jj;
            int j = o & 7, l = (o >> 3) & 63, kk = (o >> 9) & 3, n = (o >> 11) & 7;
            int row = h * 128 + kk * 32 + (l >> 4) * 8 + j;
            int col = n * 16 + (l & 15);
            v[jj] = f2bf(W1[(size_t)row * D + col]);
        }
        *reinterpret_cast<ushort4*>(&sW[o0]) = make_ushort4(v[0], v[1], v[2], v[3]);
    }
    __syncthreads();

    const int wv = t >> 6, l = t & 63;
    const int m16 = l & 15, g4 = l >> 4;

    #pragma unroll
    for (int t16 = 0; t16 < 2; ++t16) {
        const int rowbase = r0 + wv * 32 + t16 * 16;
        if (rowbase >= Nn) break;
        const int arow = rowbase + m16;
        const bool rok = arow < Nn;
        const float* rp = feat + (size_t)(rok ? arow : 0) * D;

        union { bf16x8 v; unsigned short u[8]; } afr[4];
        #pragma unroll
        for (int kk = 0; kk < 4; ++kk) {
            int k0 = kk * 32 + g4 * 8;
            float4 f0 = make_float4(0.f, 0.f, 0.f, 0.f), f1 = f0;
            if (rok) {
                f0 = *reinterpret_cast<const float4*>(rp + k0);
                f1 = *reinterpret_cast<const float4*>(rp + k0 + 4);
            }
            afr[kk].u[0] = f2bf(f0.x); afr[kk].u[1] = f2bf(f0.y);
            afr[kk].u[2] = f2bf(f0.z); afr[kk].u[3] = f2bf(f0.w);
            afr[kk].u[4] = f2bf(f1.x); afr[kk].u[5] = f2bf(f1.y);
            afr[kk].u[6] = f2bf(f1.z); afr[kk].u[7] = f2bf(f1.w);
        }

        #pragma unroll
        for (int n = 0; n < 8; ++n) {
            f32x4 acc = (f32x4){0.f, 0.f, 0.f, 0.f};
            #pragma unroll
            for (int kk = 0; kk < 4; ++kk) {
                bf16x8 bfr = *reinterpret_cast<const bf16x8*>(&sW[((n * 4 + kk) * 64 + l) * 8]);
                acc = __builtin_amdgcn_mfma_f32_16x16x32_bf16(bfr, afr[kk].v, acc, 0, 0, 0);
            }
            unsigned int lo = (unsigned int)f2bf(acc[0]) | ((unsigned int)f2bf(acc[1]) << 16);
            unsigned int hi = (unsigned int)f2bf(acc[2]) | ((unsigned int)f2bf(acc[3]) << 16);
            if (rok)
                *reinterpret_cast<uint2*>(&outp[(size_t)arow * D + n * 16 + g4 * 4]) =
                    make_uint2(lo, hi);
        }
    }
}

// ---------------- K2: edge kernel (R9-proven structure) ----------------
__device__ __forceinline__ void issue8(const unsigned short* __restrict__ A,
                                       const unsigned short* __restrict__ B,
                                       int s, int d, int quad, uint4* av, uint4* bv) {
    const unsigned short* ap = A + ((size_t)s << 7) + quad * 8;
    const unsigned short* bp = B + ((size_t)d << 7) + quad * 8;
    #pragma unroll
    for (int kk = 0; kk < 4; ++kk) {
        av[kk] = *reinterpret_cast<const uint4*>(ap + kk * 32);
        bv[kk] = *reinterpret_cast<const uint4*>(bp + kk * 32);
    }
}

__device__ __forceinline__ void edge_compute(const uint4* av, const uint4* bv,
                                             const bf16x8* wfrag, float* __restrict__ out,
                                             int g, int er, int quad) {
    f32x4 acc = (f32x4){0.f, 0.f, 0.f, 0.f};
    #pragma unroll
    for (int kk = 0; kk < 4; ++kk) {
        const unsigned int aw[4] = {av[kk].x, av[kk].y, av[kk].z, av[kk].w};
        const unsigned int bw[4] = {bv[kk].x, bv[kk].y, bv[kk].z, bv[kk].w};
        union { unsigned int w[4]; bf16x8 v; } frag;
        #pragma unroll
        for (int pp = 0; pp < 4; ++pp) {
            f32x2 za = {bflo(aw[pp]), bfhi(aw[pp])};
            f32x2 zb = {bflo(bw[pp]), bfhi(bw[pp])};
            f32x2 gl = gelu2(za + zb);
            frag.w[pp] = __builtin_amdgcn_perm(__float_as_uint(gl.y),
                                               __float_as_uint(gl.x), 0x07060302u);
        }
        acc = __builtin_amdgcn_mfma_f32_16x16x32_bf16(frag.v, wfrag[kk], acc, 0, 0, 0);
    }
    const long eb = (long)g * 16 + quad * 4;
    if (er < 5) {
        #pragma unroll
        for (int r = 0; r < 4; ++r) out[(eb + r) * 5 + er] = acc[r];
    }
}

__global__ __launch_bounds__(256, 4) void edge_fast(const unsigned short* __restrict__ A,
                                                    const unsigned short* __restrict__ B,
                                                    const int* __restrict__ src,
                                                    const int* __restrict__ dst,
                                                    const unsigned short* __restrict__ Wcbf,
                                                    float* __restrict__ out, int G) {
    const int l = threadIdx.x & 63, er = l & 15, quad = l >> 4;
    const int wid = blockIdx.x * 4 + (threadIdx.x >> 6);
    const int NW = gridDim.x * 4;
    const int q = G / NW, rr = G % NW;
    const int count = q + (wid < rr ? 1 : 0);
    if (count == 0) return;
    const int g0 = wid * q + (wid < rr ? wid : rr);
    const int glast = g0 + count - 1;

    bf16x8 wfrag[4];
    #pragma unroll
    for (int kk = 0; kk < 4; ++kk)
        wfrag[kk] = *reinterpret_cast<const bf16x8*>(&Wcbf[er * D + kk * 32 + quad * 8]);

    uint4 aA[4], bA[4], aB[4], bB[4];
    {
        int s = src[g0 * 16 + er], d = dst[g0 * 16 + er];
        issue8(A, B, s, d, quad, aA, bA);
    }
    int gN = (count > 1) ? g0 + 1 : g0;
    int sN = src[gN * 16 + er], dN = dst[gN * 16 + er];

    int i = 0;
    while (true) {
        issue8(A, B, sN, dN, quad, aB, bB);
        {
            int g2 = g0 + i + 2; if (g2 > glast) g2 = glast;
            sN = src[g2 * 16 + er]; dN = dst[g2 * 16 + er];
        }
        __builtin_amdgcn_sched_barrier(0);
        edge_compute(aA, bA, wfrag, out, g0 + i, er, quad);
        if (++i >= count) break;

        issue8(A, B, sN, dN, quad, aA, bA);
        {
            int g2 = g0 + i + 2; if (g2 > glast) g2 = glast;
            sN = src[g2 * 16 + er]; dN = dst[g2 * 16 + er];
        }
        __builtin_amdgcn_sched_barrier(0);
        edge_compute(aB, bB, wfrag, out, g0 + i, er, quad);
        if (++i >= count) break;
    }
}

// ---------------- generic edge (any E) ----------------
__global__ __launch_bounds__(256, 4) void edge_unsorted(const unsigned short* __restrict__ A,
                                                        const unsigned short* __restrict__ B,
                                                        const int* __restrict__ src,
                                                        const int* __restrict__ dst,
                                                        const unsigned short* __restrict__ Wcbf,
                                                        float* __restrict__ out, int E) {
    const int l    = threadIdx.x & 63;
    const int er   = l & 15;
    const int quad = l >> 4;
    const int wid  = blockIdx.x * 4 + (threadIdx.x >> 6);
    const int nw   = gridDim.x * 4;

    bf16x8 wfrag[4];
    #pragma unroll
    for (int kk = 0; kk < 4; ++kk)
        wfrag[kk] = *reinterpret_cast<const bf16x8*>(&Wcbf[er * D + kk * 32 + quad * 8]);

    const int P = (E + 15) >> 4;
    const int Emax = E - 1;
    for (int p = wid; p < P; p += nw) {
        int ia = p * 16 + er;
        int s = src[min(ia, Emax)], d = dst[min(ia, Emax)];
        uint4 av[4], bv[4];
        issue8(A, B, s, d, quad, av, bv);

        f32x4 acc = (f32x4){0.f, 0.f, 0.f, 0.f};
        #pragma unroll
        for (int kk = 0; kk < 4; ++kk) {
            const unsigned int aw[4] = {av[kk].x, av[kk].y, av[kk].z, av[kk].w};
            const unsigned int bw[4] = {bv[kk].x, bv[kk].y, bv[kk].z, bv[kk].w};
            union { unsigned int w[4]; bf16x8 v; } frag;
            #pragma unroll
            for (int pp = 0; pp < 4; ++pp) {
                f32x2 za = {bflo(aw[pp]), bfhi(aw[pp])};
                f32x2 zb = {bflo(bw[pp]), bfhi(bw[pp])};
                f32x2 gl = gelu2(za + zb);
                frag.w[pp] = __builtin_amdgcn_perm(__float_as_uint(gl.y),
                                                   __float_as_uint(gl.x), 0x07060302u);
            }
            acc = __builtin_amdgcn_mfma_f32_16x16x32_bf16(frag.v, wfrag[kk], acc, 0, 0, 0);
        }
        #pragma unroll
        for (int r = 0; r < 4; ++r) {
            int e = p * 16 + quad * 4 + r;
            if (er < 5 && e < E) out[(size_t)e * 5 + er] = acc[r];
        }
    }
}

// ---------------- fallback (ws too small): fully fused per-edge ----------------
__global__ __launch_bounds__(256) void fused_fallback(const float* __restrict__ uf,
                                                      const float* __restrict__ vf,
                                                      const int* __restrict__ src,
                                                      const int* __restrict__ dst,
                                                      const float* __restrict__ W1,
                                                      const float* __restrict__ W2,
                                                      const float* __restrict__ Wp,
                                                      float* __restrict__ out, int E) {
    __shared__ unsigned short sW[256 * 128];
    __shared__ float sWc[5 * 128];
    __shared__ float sH[4][256];
    const int t = threadIdx.x;
    #pragma unroll
    for (int i = 0; i < 32; ++i) {
        int f = (i * 256 + t) * 4;
        float4 v = *reinterpret_cast<const float4*>(&W1[f]);
        sW[f + 0] = f2bf(v.x); sW[f + 1] = f2bf(v.y);
        sW[f + 2] = f2bf(v.z); sW[f + 3] = f2bf(v.w);
    }
    for (int idx = t; idx < 640; idx += 256) {
        int c = idx >> 7, k = idx & 127;
        float a = 0.f;
        for (int m = 0; m < 128; ++m) a += W2[k * 128 + m] * Wp[m * 5 + c];
        sWc[c * 128 + k] = a;
    }
    __syncthreads();
    const int wid = t >> 6, l = t & 63;
    const int nw = gridDim.x * 4;
    for (int e = blockIdx.x * 4 + wid; e < E; e += nw) {
        int s = src[e], d0 = dst[e];
        float2 hu = *reinterpret_cast<const float2*>(&uf[(size_t)s * 128 + 2 * l]);
        float2 hv = *reinterpret_cast<const float2*>(&vf[(size_t)d0 * 128 + 2 * l]);
        sH[wid][2 * l] = hu.x; sH[wid][2 * l + 1] = hu.y;
        sH[wid][128 + 2 * l] = hv.x; sH[wid][128 + 2 * l + 1] = hv.y;
        __builtin_amdgcn_wave_barrier();
        float z0 = 0.f, z1 = 0.f;
        for (int k = 0; k < 256; ++k) {
            float h = sH[wid][k];
            z0 += h * __uint_as_float((unsigned int)sW[k * 128 + l] << 16);
            z1 += h * __uint_as_float((unsigned int)sW[k * 128 + l + 64] << 16);
        }
        float g0 = gelu_erf(z0), g1 = gelu_erf(z1);
        float acc[5];
        #pragma unroll
        for (int c = 0; c < 5; ++c)
            acc[c] = g0 * sWc[c * 128 + l] + g1 * sWc[c * 128 + l + 64];
        #pragma unroll
        for (int c = 0; c < 5; ++c) {
            float v = acc[c];
            v += __shfl_xor(v, 1);  v += __shfl_xor(v, 2);
            v += __shfl_xor(v, 4);  v += __shfl_xor(v, 8);
            v += __shfl_xor(v, 16); v += __shfl_xor(v, 32);
            acc[c] = v;
        }
        float v = acc[0];
        if (l == 1) v = acc[1];
        if (l == 2) v = acc[2];
        if (l == 3) v = acc[3];
        if (l == 4) v = acc[4];
        if (l < 5) out[(size_t)e * 5 + l] = v;
        __builtin_amdgcn_wave_barrier();
    }
}

extern "C" void kernel_launch(void* const* d_in, const int* in_sizes, int n_in,
                              void* d_out, int out_size, void* d_ws, size_t ws_size,
                              hipStream_t stream) {
    const float* ufeat = (const float*)d_in[0];
    const float* ifeat = (const float*)d_in[1];
    const int*   src   = (const int*)d_in[2];
    const int*   dst   = (const int*)d_in[3];
    const float* W1    = (const float*)d_in[4];
    const float* W2    = (const float*)d_in[5];
    const float* Wp    = (const float*)d_in[6];
    float* out = (float*)d_out;

    const int NU = in_sizes[0] / D;
    const int NM = in_sizes[1] / D;
    const int E  = in_sizes[2];

    size_t cur = 0;
    auto alloc = [&](size_t bytes) { size_t o = cur; cur = (cur + bytes + 255) & ~(size_t)255; return o; };
    size_t off_Wc = alloc(4096);
    size_t off_A  = alloc((size_t)NU * D * 2);
    size_t off_B  = alloc((size_t)NM * D * 2);
    size_t need   = cur;

    if (ws_size >= need) {
        unsigned short* Wcbf = (unsigned short*)((char*)d_ws + off_Wc);
        unsigned short* Abf  = (unsigned short*)((char*)d_ws + off_A);
        unsigned short* Bbf  = (unsigned short*)((char*)d_ws + off_B);
        int nbU = (NU + 255) / 256, nbM = (NM + 255) / 256;

        node_wc<<<dim3(nbU + nbM + 1), dim3(512), 0, stream>>>(ufeat, ifeat, W1, W2, Wp,
                                                               NU, NM, nbU, nbM,
                                                               Abf, Bbf, Wcbf);
        if ((E & 15) == 0 && E >= 16) {
            edge_fast<<<dim3(1024), dim3(256), 0, stream>>>(Abf, Bbf, src, dst, Wcbf,
                                                            out, E >> 4);
        } else {
            edge_unsorted<<<dim3(2048), dim3(256), 0, stream>>>(Abf, Bbf, src, dst, Wcbf, out, E);
        }
    } else {
        fused_fallback<<<dim3(4096), dim3(256), 0, stream>>>(ufeat, ifeat, src, dst,
                                                             W1, W2, Wp, out, E);
    }
}